// Round 2
// baseline (19.457 us; speedup 1.0000x reference)
//
#include <hip/hip_runtime.h>
#include <hip/hip_bf16.h>

// ZeroOneLoss: out = mean_i( input[i, targets[i]] > 0 )
// B = 16384, V = 32000.
//
// Single-dispatch design: one block of 1024 threads does the entire job
// (gather + reduce + write). Removes the memset node and the finalize node
// from the graph (~5 us each). No workspace, no atomics -> deterministic.

__global__ __launch_bounds__(1024) void zol_single(
        const float* __restrict__ input,
        const int* __restrict__ targets,
        float* __restrict__ out,
        int B, long long V) {
    const int tid = threadIdx.x;
    const int T = 1024;
    int cnt = 0;

    if (B == T * 16) {
        // Fast path: 16 consecutive rows per thread; targets via 4x int4.
        const int base = tid * 16;
        const int4* t4 = reinterpret_cast<const int4*>(targets + base);
        int t[16];
        int4 a = t4[0], b = t4[1], c = t4[2], d = t4[3];
        t[0]=a.x; t[1]=a.y; t[2]=a.z; t[3]=a.w;
        t[4]=b.x; t[5]=b.y; t[6]=b.z; t[7]=b.w;
        t[8]=c.x; t[9]=c.y; t[10]=c.z; t[11]=c.w;
        t[12]=d.x; t[13]=d.y; t[14]=d.z; t[15]=d.w;
        float v[16];
        #pragma unroll
        for (int k = 0; k < 16; ++k) {
            v[k] = input[(long long)(base + k) * V + (long long)t[k]];
        }
        #pragma unroll
        for (int k = 0; k < 16; ++k) {
            cnt += (v[k] > 0.0f) ? 1 : 0;
        }
    } else {
        // Generic fallback (not used at the bench shape).
        for (int i = tid; i < B; i += T) {
            int t = targets[i];
            float v = input[(long long)i * V + (long long)t];
            cnt += (v > 0.0f) ? 1 : 0;
        }
    }

    // Wave (64-lane) shuffle reduction.
    #pragma unroll
    for (int off = 32; off > 0; off >>= 1) {
        cnt += __shfl_down(cnt, off, 64);
    }

    __shared__ int wsum[16];
    if ((tid & 63) == 0) wsum[tid >> 6] = cnt;
    __syncthreads();

    if (tid == 0) {
        int tot = 0;
        #pragma unroll
        for (int w = 0; w < 16; ++w) tot += wsum[w];
        out[0] = (float)tot / (float)B;
    }
}

extern "C" void kernel_launch(void* const* d_in, const int* in_sizes, int n_in,
                              void* d_out, int out_size, void* d_ws, size_t ws_size,
                              hipStream_t stream) {
    const float* input = (const float*)d_in[0];
    const int* targets = (const int*)d_in[1];
    float* out = (float*)d_out;

    const int B = in_sizes[1];                                   // 16384
    const long long V = (long long)in_sizes[0] / (long long)B;   // 32000

    zol_single<<<1, 1024, 0, stream>>>(input, targets, out, B, V);
}

// Round 3
// 14.397 us; speedup vs baseline: 1.3515x; 1.3515x over previous
//
#include <hip/hip_runtime.h>
#include <hip/hip_bf16.h>

// ZeroOneLoss: out = mean_i( input[i, targets[i]] > 0 ),  B=16384, V=32000.
//
// 2 graph nodes total:
//   node 1: hipMemsetAsync(d_out, 0, 4)   -- zero the accumulator each call
//   node 2: gather kernel, 64 blocks x 256 threads (1 row/thread) spread
//           across 64 CUs so the 16384 scattered HBM loads are one
//           latency-shot (~1 us), not serialized on a single CU (R2 lesson).
//
// Cross-block reduce: per-wave ballot+popcount, then float atomicAdd of
// popc/16384 into d_out. Every term is k * 2^-14 and all partial sums are
// exact in fp32 (<= 1.0), so the result is bit-identical regardless of
// atomic ordering -> deterministic across graph replays.

__global__ void zol_gather(const float* __restrict__ input,
                           const int* __restrict__ targets,
                           float* __restrict__ out,
                           int B, long long V, float invB) {
    int i = blockIdx.x * blockDim.x + threadIdx.x;
    bool pred = false;
    if (i < B) {
        int t = targets[i];
        pred = input[(long long)i * V + (long long)t] > 0.0f;
    }
    unsigned long long m = __ballot(pred);
    if ((threadIdx.x & 63) == 0) {
        int c = (int)__popcll(m);
        if (c) atomicAdd(out, (float)c * invB);
    }
}

extern "C" void kernel_launch(void* const* d_in, const int* in_sizes, int n_in,
                              void* d_out, int out_size, void* d_ws, size_t ws_size,
                              hipStream_t stream) {
    const float* input = (const float*)d_in[0];
    const int* targets = (const int*)d_in[1];
    float* out = (float*)d_out;

    const int B = in_sizes[1];                                   // 16384
    const long long V = (long long)in_sizes[0] / (long long)B;   // 32000

    hipMemsetAsync(out, 0, sizeof(float), stream);

    const int block = 256;
    const int grid = (B + block - 1) / block;                    // 64 blocks
    zol_gather<<<grid, block, 0, stream>>>(input, targets, out, B, V,
                                           1.0f / (float)B);
}